// Round 1
// baseline (463.916 us; speedup 1.0000x reference)
//
#include <hip/hip_runtime.h>
#include <hip/hip_bf16.h>

// GCN over Block-CSR adjacency. ALL I/O BUFFERS ARE FLOAT32 (reference dtypes).
// Compute: bf16 MFMA, fp32 accumulate; intermediates stored bf16.
//
// Round 7: spmm_ln v4. Evidence from R6 counters: VGPR=64 (compiler defeated the
// "gathers in flight" design AGAIN by targeting 8 waves/EU), MfmaUtil 3.5%,
// VALUBusy 13%, HBM 48% -> latency-bound with ~1-2 outstanding gathers/wave.
//  - __launch_bounds__(256,2): 256-VGPR budget so fragments can stay live.
//  - sched_barrier(0) phase fences: per row, issue-next / compute-current pipeline
//    (bc_next -> kp23 gathers -> A_next raw f32 -> MFMA kp01 -> kp01_next gathers
//     -> MFMA kp23 -> LN). ~20-24 loads in flight per wave, counted vmcnt waits.
//  - A-prefetch kept as raw f32x4 (convert deferred to use) so no vmcnt(0) drain.
//  - 4 block-rows per wave-pair (grid 1024) so the pipeline crosses rows.
//  - __syncthreads (emits vmcnt(0): would drain the prefetch queue every row)
//    replaced by lgkmcnt(0)-only + raw s_barrier; LN partial-sum LDS is
//    double-buffered by row parity so one barrier per row suffices.
//
// z_bt layout: per 16-row block rb, store [F][16] so SpMM B-fragments are 16B loads.
// d_ws: zbt + h (bf16) = exactly 128 MiB. Transposed bf16 weights (229 KB) in
// d_out-as-scratch; consumed before spmm_out overwrites d_out (stream-ordered).

typedef __bf16 bf16;
typedef bf16 bf16x8 __attribute__((ext_vector_type(8)));
typedef bf16 bf16x4 __attribute__((ext_vector_type(4)));
typedef float f32x4 __attribute__((ext_vector_type(4)));

#define N_NODES 131072
#define BRQ 8192      // block rows (= N/16)
#define KNZ 8         // nonzero blocks per block row
#define IN_F 128
#define HID 256
#define NCLS 64

#define SB() __builtin_amdgcn_sched_barrier(0)

static __device__ __forceinline__ f32x4 mfma16(bf16x8 a, bf16x8 b, f32x4 c) {
  return __builtin_amdgcn_mfma_f32_16x16x32_bf16(a, b, c, 0, 0, 0);
}

static __device__ __forceinline__ bf16x8 load8(const bf16* p) {
  return *(const bf16x8*)p;
}
static __device__ __forceinline__ bf16x8 cvt8(f32x4 a0, f32x4 a1) {
  bf16x8 r;
  r[0] = (bf16)a0[0]; r[1] = (bf16)a0[1]; r[2] = (bf16)a0[2]; r[3] = (bf16)a0[3];
  r[4] = (bf16)a1[0]; r[5] = (bf16)a1[1]; r[6] = (bf16)a1[2]; r[7] = (bf16)a1[3];
  return r;
}
static __device__ __forceinline__ bf16x8 load8(const float* p) {
  f32x4 a0 = *(const f32x4*)p;
  f32x4 a1 = *(const f32x4*)(p + 4);
  return cvt8(a0, a1);
}

// ---------------- fused transpose + f32->bf16 convert for all 3 W matrices -------
// sizes: W0 128x256 (32768), W1 256x256 (65536), W2 256x64 (16384) => 114688 elems
__global__ void transpose_all(const float* __restrict__ W0, const float* __restrict__ W1,
                              const float* __restrict__ W2, bf16* __restrict__ w0t,
                              bf16* __restrict__ w1t, bf16* __restrict__ w2t) {
  int idx = blockIdx.x * 256 + threadIdx.x;
  if (idx < 32768) {
    int r = idx >> 8, c = idx & 255;            // 128 x 256
    w0t[c * 128 + r] = (bf16)W0[idx];
  } else if (idx < 98304) {
    int j = idx - 32768; int r = j >> 8, c = j & 255;  // 256 x 256
    w1t[c * 256 + r] = (bf16)W1[j];
  } else {
    int j = idx - 98304; int r = j >> 6, c = j & 63;   // 256 x 64
    w2t[c * 256 + r] = (bf16)W2[j];
  }
}

// ---------------- dense GEMM: B-stationary registers ------------------------------
// Zbt[rt][col][r] = X[N,KIN] @ W[KIN,FOUT]; WT = W^T [FOUT,KIN] bf16 row-major.
template<typename TA, int KIN, int FOUT, int GRID>
__global__ __launch_bounds__(256) void gemm_bt(const TA* __restrict__ X,
                                               const bf16* __restrict__ WT,
                                               bf16* __restrict__ Zbt) {
  constexpr int CG  = FOUT / 64;          // 64-col groups
  constexpr int KS  = KIN / 32;           // K steps
  constexpr int RTS = GRID * 4 / CG;      // row-tile stride (waves per col group)
  constexpr int NT  = BRQ / RTS;          // row-tiles per wave

  const int wave = threadIdx.x >> 6;
  const int lane = threadIdx.x & 63;
  const int l15  = lane & 15;
  const int quad = lane >> 4;
  const int gw   = blockIdx.x * 4 + wave;
  const int cg   = gw % CG;
  const int rt0  = gw / CG;

  const bf16* __restrict__ wbase = WT + (long)(cg * 64 + l15) * KIN + quad * 8;
  bf16x8 bfr[KS][4];
#pragma unroll
  for (int k = 0; k < KS; ++k)
#pragma unroll
    for (int t = 0; t < 4; ++t)
      bfr[k][t] = *(const bf16x8*)(wbase + t * (16 * KIN) + k * 32);

  const TA* __restrict__ xbase = X + (long)l15 * KIN + quad * 8;

  bf16x8 aw[2][KS];
#pragma unroll
  for (int k = 0; k < KS; ++k)
    aw[0][k] = load8(xbase + (long)rt0 * (16 * KIN) + k * 32);

#pragma unroll
  for (int it = 0; it < NT; ++it) {
    const int rt = rt0 + it * RTS;
    if (it + 1 < NT) {
      const long xoff = (long)(rt + RTS) * (16 * KIN);
#pragma unroll
      for (int k = 0; k < KS; ++k)
        aw[(it + 1) & 1][k] = load8(xbase + xoff + k * 32);
    }
    f32x4 acc[4] = {};
#pragma unroll
    for (int k = 0; k < KS; ++k)
#pragma unroll
      for (int t = 0; t < 4; ++t)
        acc[t] = mfma16(aw[it & 1][k], bfr[k][t], acc[t]);
#pragma unroll
    for (int t = 0; t < 4; ++t) {
      int col = cg * 64 + t * 16 + l15;
      bf16x4 v;
#pragma unroll
      for (int i = 0; i < 4; ++i) v[i] = (bf16)acc[t][i];
      *(bf16x4*)(Zbt + ((long)rt * FOUT + col) * 16 + quad * 4) = v;
    }
  }
}

// ---------------- SpMM + bias + ReLU + LayerNorm (F = HID = 256) v4 ---------------
// Block = 4 waves = 2 block-rows per iteration, NITER=4 iterations (8 rows/WG).
// Wave (pair,ch): block-row b = b0 + 2*it, columns [ch*128, ch*128+128).
// Software pipeline with sched_barrier fences; raw s_barrier (lgkm-only drain)
// keeps next-row gathers in flight across the LN exchange.
#define NITER 4

__global__ __launch_bounds__(256, 2) void spmm_ln(const float* __restrict__ Abv,
                                                  const int*   __restrict__ Abc,
                                                  const bf16*  __restrict__ Zbt,
                                                  const float* __restrict__ bias,
                                                  const float* __restrict__ gamma,
                                                  const float* __restrict__ beta,
                                                  bf16* __restrict__ H) {
  const int wave = threadIdx.x >> 6;
  const int lane = threadIdx.x & 63;
  const int l15  = lane & 15;
  const int quad = lane >> 4;
  const int pair = wave >> 1;
  const int ch   = wave & 1;               // column half
  const int cst  = (quad & 1) * 8;
  const int half = quad >> 1;

  __shared__ float S[2][4][16], SS[2][4][16];

  const int b0 = blockIdx.x * (2 * NITER) + pair;
  const char* zbase = (const char*)Zbt;
  const unsigned foff = (unsigned)(ch * 128 + l15) * 32;   // byte offset of t=0 frag

  // ---------------- prologue: row b0 meta + A + kp0/1 gathers ----------------
  bf16x8   afr[4];
  unsigned zoff[4];
  {
    const float* ab = Abv + (long)b0 * (KNZ * 256) + l15 * 16 + cst;
    const int*   bc = Abc + b0 * KNZ;
#pragma unroll
    for (int kp = 0; kp < 4; ++kp) {
      int blk = 2 * kp + half;
      afr[kp]  = load8(ab + blk * 256);
      zoff[kp] = (unsigned)bc[blk] * (HID * 16 * 2) + (unsigned)cst * 2;
    }
  }
  bf16x8 buf0[16];   // kp0,1 fragments for current row
#pragma unroll
  for (int kp = 0; kp < 2; ++kp)
#pragma unroll
    for (int t = 0; t < 8; ++t)
      buf0[kp * 8 + t] = *(const bf16x8*)(zbase + zoff[kp] + foff + (unsigned)t * 512);
  SB();

#pragma unroll
  for (int it = 0; it < NITER; ++it) {
    const int  b    = b0 + 2 * it;
    const bool more = (it + 1 < NITER);

    // --- phase 1: next-row block-col ids (issued FIRST so waiting on them
    //     later doesn't imply draining the gather queue) ---
    int bcn[4];
    if (more) {
      const int* bc = Abc + (b + 2) * KNZ;
#pragma unroll
      for (int kp = 0; kp < 4; ++kp) bcn[kp] = bc[2 * kp + half];
    }
    SB();
    // --- phase 2: kp2/3 gathers for current row ---
    bf16x8 buf1[16];
#pragma unroll
    for (int kp = 2; kp < 4; ++kp)
#pragma unroll
      for (int t = 0; t < 8; ++t)
        buf1[(kp - 2) * 8 + t] = *(const bf16x8*)(zbase + zoff[kp] + foff + (unsigned)t * 512);
    SB();
    // --- phase 3: next-row A loads, RAW f32 (convert deferred: converting here
    //     would force a wait that drains the whole vm queue) ---
    f32x4 araw[4][2];
    if (more) {
      const float* ab = Abv + (long)(b + 2) * (KNZ * 256) + l15 * 16 + cst;
#pragma unroll
      for (int kp = 0; kp < 4; ++kp) {
        const float* p = ab + (2 * kp + half) * 256;
        araw[kp][0] = *(const f32x4*)p;
        araw[kp][1] = *(const f32x4*)(p + 4);
      }
    }
    SB();
    // --- phase 4: MFMA kp0/1 (counted vmcnt wait on buf0 only) ---
    f32x4 acc[8] = {};
#pragma unroll
    for (int kp = 0; kp < 2; ++kp)
#pragma unroll
      for (int t = 0; t < 8; ++t)
        acc[t] = mfma16(afr[kp], buf0[kp * 8 + t], acc[t]);
    SB();
    // --- phase 5: next-row kp0/1 gathers (needs bcn arrived; bcn was issued
    //     before buf1 so this wait keeps buf1 + araw in flight) ---
    if (more) {
#pragma unroll
      for (int kp = 0; kp < 4; ++kp)
        zoff[kp] = (unsigned)bcn[kp] * (HID * 16 * 2) + (unsigned)cst * 2;
#pragma unroll
      for (int kp = 0; kp < 2; ++kp)
#pragma unroll
        for (int t = 0; t < 8; ++t)
          buf0[kp * 8 + t] = *(const bf16x8*)(zbase + zoff[kp] + foff + (unsigned)t * 512);
    }
    SB();
    // --- phase 6: MFMA kp2/3, then rotate A (convert raw f32 -> bf16; waits
    //     only up to araw, next-row buf0 gathers stay in flight) ---
#pragma unroll
    for (int kp = 0; kp < 2; ++kp)
#pragma unroll
      for (int t = 0; t < 8; ++t)
        acc[t] = mfma16(afr[2 + kp], buf1[kp * 8 + t], acc[t]);
    if (more) {
#pragma unroll
      for (int kp = 0; kp < 4; ++kp) afr[kp] = cvt8(araw[kp][0], araw[kp][1]);
    }
    SB();
    // --- phase 7: bias + relu + LayerNorm + store ---
    float ps[4] = {0.f, 0.f, 0.f, 0.f}, pss[4] = {0.f, 0.f, 0.f, 0.f};
#pragma unroll
    for (int t = 0; t < 8; ++t) {
      float bi = bias[ch * 128 + t * 16 + l15];
#pragma unroll
      for (int i = 0; i < 4; ++i) {
        float v = acc[t][i] + bi;
        v = v > 0.f ? v : 0.f;
        acc[t][i] = v;
        ps[i] += v;
        pss[i] += v * v;
      }
    }
#pragma unroll
    for (int m = 1; m < 16; m <<= 1) {
#pragma unroll
      for (int i = 0; i < 4; ++i) {
        ps[i]  += __shfl_xor(ps[i], m, 64);
        pss[i] += __shfl_xor(pss[i], m, 64);
      }
    }
    const int par = it & 1;
    if (l15 == 0) {
#pragma unroll
      for (int i = 0; i < 4; ++i) {
        S[par][wave][quad * 4 + i]  = ps[i];
        SS[par][wave][quad * 4 + i] = pss[i];
      }
    }
    // raw barrier: drain LDS writes only (lgkmcnt), keep vm gather queue alive.
    __builtin_amdgcn_sched_barrier(0);
    asm volatile("s_waitcnt lgkmcnt(0)" ::: "memory");
    __builtin_amdgcn_s_barrier();
    __builtin_amdgcn_sched_barrier(0);
    float gv[8], bvv[8];
#pragma unroll
    for (int t = 0; t < 8; ++t) {
      int f = ch * 128 + t * 16 + l15;
      gv[t]  = gamma[f];
      bvv[t] = beta[f];
    }
#pragma unroll
    for (int i = 0; i < 4; ++i) {
      int r = quad * 4 + i;
      float s    = S[par][wave][r] + S[par][wave ^ 1][r];
      float ss   = SS[par][wave][r] + SS[par][wave ^ 1][r];
      float mu   = s * (1.f / 256.f);
      float var  = ss * (1.f / 256.f) - mu * mu;
      float rstd = rsqrtf(var + 1e-5f);
      bf16* hrow = H + (long)(b * 16 + r) * HID;
#pragma unroll
      for (int t = 0; t < 8; ++t) {
        int f = ch * 128 + t * 16 + l15;
        float y = (acc[t][i] - mu) * rstd * gv[t] + bvv[t];
        hrow[f] = (bf16)y;
      }
    }
    SB();
  }
}

// ---------------- final SpMM + bias (F = NCLS = 64), row-major FLOAT32 out -------
__global__ __launch_bounds__(256) void spmm_out(const float* __restrict__ Abv,
                                                const int*   __restrict__ Abc,
                                                const bf16*  __restrict__ Zbt,  // [BRQ,64,16]
                                                const float* __restrict__ bias, // [64]
                                                float* __restrict__ out) {      // [N,64] f32
  const int wave = threadIdx.x >> 6;
  const int b    = blockIdx.x * 4 + wave;   // one block-row per wave
  const int lane = threadIdx.x & 63;
  const int l15  = lane & 15;
  const int quad = lane >> 4;

  const int*   bc    = Abc + b * KNZ;
  const int    cst   = (quad & 1) * 8;
  const int    half  = quad >> 1;
  const float* abase = Abv + (long)b * (KNZ * 256) + l15 * 16 + cst;

  bf16x8 afr[4];
  long   zb[4];
#pragma unroll
  for (int kp = 0; kp < 4; ++kp) {
    int blk = 2 * kp + half;
    afr[kp] = load8(abase + blk * 256);
    zb[kp]  = (long)bc[blk] * (NCLS * 16) + cst;
  }
  bf16x8 bfr[4][4];
#pragma unroll
  for (int kp = 0; kp < 4; ++kp)
#pragma unroll
    for (int t = 0; t < 4; ++t) {
      int f = t * 16 + l15;
      bfr[kp][t] = *(const bf16x8*)(Zbt + zb[kp] + f * 16);
    }

  f32x4 acc[4] = {};
#pragma unroll
  for (int kp = 0; kp < 4; ++kp)
#pragma unroll
    for (int t = 0; t < 4; ++t)
      acc[t] = mfma16(afr[kp], bfr[kp][t], acc[t]);

#pragma unroll
  for (int t = 0; t < 4; ++t) {
    int f = t * 16 + l15;
    float bi = bias[f];
#pragma unroll
    for (int i = 0; i < 4; ++i) {
      out[(long)(b * 16 + quad * 4 + i) * NCLS + f] = acc[t][i] + bi;
    }
  }
}

extern "C" void kernel_launch(void* const* d_in, const int* in_sizes, int n_in,
                              void* d_out, int out_size, void* d_ws, size_t ws_size,
                              hipStream_t stream) {
  const float* features = (const float*)d_in[0];
  const float* bvals    = (const float*)d_in[1];
  const float* W0       = (const float*)d_in[2];
  const float* b0       = (const float*)d_in[3];
  const float* W1       = (const float*)d_in[4];
  const float* b1       = (const float*)d_in[5];
  const float* W2       = (const float*)d_in[6];
  const float* b2       = (const float*)d_in[7];
  const float* g0       = (const float*)d_in[8];
  const float* beta0    = (const float*)d_in[9];
  const float* g1       = (const float*)d_in[10];
  const float* beta1    = (const float*)d_in[11];
  const int*   bcols    = (const int*)d_in[12];
  float* outp = (float*)d_out;

  // d_ws: zbt [N*HID] + h [N*HID] bf16 = exactly 128 MiB.
  bf16* zbt = (bf16*)d_ws;
  bf16* h   = zbt + (size_t)N_NODES * HID;

  // Transposed bf16 weights in d_out-as-scratch (229 KB of the 33.6 MB f32 output
  // buffer). All reads complete before spmm_out overwrites d_out (stream order).
  bf16* w0t = (bf16*)d_out;         // IN_F*HID  = 32768 elems
  bf16* w1t = w0t + IN_F * HID;     // HID*HID   = 65536 elems
  bf16* w2t = w1t + HID * HID;      // HID*NCLS  = 16384 elems

  transpose_all<<<dim3(448), dim3(256), 0, stream>>>(W0, W1, W2, w0t, w1t, w2t);

  // layer 0: 1024 blocks, CG=4 -> 8 row-tiles/wave
  gemm_bt<float, IN_F, HID, 1024><<<dim3(1024), dim3(256), 0, stream>>>(features, w0t, zbt);
  spmm_ln<<<dim3(BRQ / (2 * NITER)), dim3(256), 0, stream>>>(bvals, bcols, zbt, b0, g0, beta0, h);
  // layer 1
  gemm_bt<bf16, HID, HID, 1024><<<dim3(1024), dim3(256), 0, stream>>>(h, w1t, zbt);
  spmm_ln<<<dim3(BRQ / (2 * NITER)), dim3(256), 0, stream>>>(bvals, bcols, zbt, b1, g1, beta1, h);
  // output layer: CG=1, 512 blocks -> 4 row-tiles/wave
  gemm_bt<bf16, HID, NCLS, 512><<<dim3(512), dim3(256), 0, stream>>>(h, w2t, zbt);
  spmm_out<<<dim3(BRQ / 4), dim3(256), 0, stream>>>(bvals, bcols, zbt, b2, outp);
}